// Round 3
// baseline (18677.452 us; speedup 1.0000x reference)
//
#include <hip/hip_runtime.h>
#include <hip/hip_bf16.h>
#include <math.h>

// Model dims
#define NBLK 6
#define BS   200
#define NHID 1200
#define NINP 2400
#define TT   32
#define BZ   32
#define NTOK 16000
#define NG   4800      // NBLK*4*BS
#define ROWS 1024      // TT*BZ
#define L1D  1600      // 8 heads * 200

typedef __bf16 bf16_t;
typedef __attribute__((ext_vector_type(8))) __bf16 bf16x8;
typedef __attribute__((ext_vector_type(4))) __bf16 bf16x4;
typedef __attribute__((ext_vector_type(4))) float f32x4;

__device__ __forceinline__ float sigmoidf_(float x) { return 1.0f / (1.0f + expf(-x)); }

// ---------------------------------------------------------------------------
// split one float4 into P bf16 planes and store to LDS (vector ds_write)
// ---------------------------------------------------------------------------
template <int P>
__device__ __forceinline__ void store_split(bf16_t (*S)[4096], int off, float4 v) {
    float f[4] = {v.x, v.y, v.z, v.w};
    bf16x4 h, m, l;
    #pragma unroll
    for (int j = 0; j < 4; j++) {
        float x = f[j];
        bf16_t hh = (bf16_t)x;
        h[j] = hh;
        if constexpr (P >= 3) {
            float r = x - (float)hh;
            bf16_t mm_ = (bf16_t)r;
            m[j] = mm_;
            l[j] = (bf16_t)(r - (float)mm_);
        }
    }
    *(bf16x4*)&S[0][off] = h;
    if constexpr (P >= 3) {
        *(bf16x4*)&S[1][off] = m;
        *(bf16x4*)&S[2][off] = l;
    }
}

// ---------------------------------------------------------------------------
// MFMA GEMM with on-the-fly fp32 -> bf16xP split (P=1: plain bf16; P=3:
// 6-pass "bf16x3" with ~fp32-level accuracy).
// C[M,N] fp32 = A[M,K] fp32 @ Bmat^T (+bias1+bias2)
//   BT_SRC=false: B buffer is (N,K) row-major (Bmat[n][k] = B[n*K+k])
//   BT_SRC=true : B buffer is (K,N) row-major (Bmat[n][k] = B[k*N+n])
// a_gather: optional row gather for A (embedding fusion).
// Tile 128x128, BK=32, 4 waves (2x2 of 64x64). K arbitrary %4, M/N guarded.
// ---------------------------------------------------------------------------
template <int P, bool BT_SRC>
__global__ __launch_bounds__(256) void gemm_mfma_kernel(
    const float* __restrict__ A, const float* __restrict__ B,
    const float* __restrict__ bias1, const float* __restrict__ bias2,
    float* __restrict__ C, int M, int N, int K, int ldc,
    const int* __restrict__ a_gather)
{
    __shared__ bf16_t As[P][4096];
    __shared__ bf16_t Bs[P][4096];
    const int tid = threadIdx.x;
    const int wave = tid >> 6, lane = tid & 63;
    const int m0 = blockIdx.y * 128, n0 = blockIdx.x * 128;
    const int wm = (wave & 1) * 64, wn = (wave >> 1) * 64;
    const int fr = lane & 15, fq = (lane >> 4) * 8;

    f32x4 acc[4][4] = {};

    for (int k0 = 0; k0 < K; k0 += 32) {
        // ---- stage A tile (128 rows x 32 k), row-major source ----
        #pragma unroll
        for (int i = 0; i < 4; i++) {
            int e = i * 256 + tid;
            int mm = e >> 3, k4 = (e & 7) << 2;
            int row = min(m0 + mm, M - 1);
            long ar = a_gather ? (long)a_gather[row] * K : (long)row * K;
            int kk = k0 + k4;
            float4 v = make_float4(0.f, 0.f, 0.f, 0.f);
            if (kk < K) v = *(const float4*)&A[ar + kk];
            store_split<P>(As, mm * 32 + k4, v);
        }
        // ---- stage B tile (128 n x 32 k) ----
        if constexpr (!BT_SRC) {
            #pragma unroll
            for (int i = 0; i < 4; i++) {
                int e = i * 256 + tid;
                int nn = e >> 3, k4 = (e & 7) << 2;
                int row = min(n0 + nn, N - 1);
                int kk = k0 + k4;
                float4 v = make_float4(0.f, 0.f, 0.f, 0.f);
                if (kk < K) v = *(const float4*)&B[(long)row * K + kk];
                store_split<P>(Bs, nn * 32 + k4, v);
            }
        } else {
            #pragma unroll
            for (int i = 0; i < 4; i++) {
                int nn = tid & 127;
                int kb = (((i * 256 + tid) >> 7) << 2);  // 0,4,...,28
                int n = n0 + nn;
                float4 v;
                float f[4];
                #pragma unroll
                for (int j = 0; j < 4; j++) {
                    int kk = k0 + kb + j;
                    f[j] = (kk < K && n < N) ? B[(long)kk * N + n] : 0.f;
                }
                v = make_float4(f[0], f[1], f[2], f[3]);
                store_split<P>(Bs, nn * 32 + kb, v);
            }
        }
        __syncthreads();
        // ---- 1 or 6 MFMA passes: (pa,pb) with pa+pb <= P-1 ----
        #pragma unroll
        for (int pa = 0; pa < P; pa++) {
            bf16x8 af[4];
            #pragma unroll
            for (int mi = 0; mi < 4; mi++)
                af[mi] = *(const bf16x8*)&As[pa][(wm + mi * 16 + fr) * 32 + fq];
            #pragma unroll
            for (int pb = 0; pb < P - pa; pb++) {
                bf16x8 bfv[4];
                #pragma unroll
                for (int ni = 0; ni < 4; ni++)
                    bfv[ni] = *(const bf16x8*)&Bs[pb][(wn + ni * 16 + fr) * 32 + fq];
                #pragma unroll
                for (int mi = 0; mi < 4; mi++)
                    #pragma unroll
                    for (int ni = 0; ni < 4; ni++)
                        acc[mi][ni] = __builtin_amdgcn_mfma_f32_16x16x32_bf16(
                            af[mi], bfv[ni], acc[mi][ni], 0, 0, 0);
            }
        }
        __syncthreads();
    }

    // epilogue: C/D map col=lane&15, row=(lane>>4)*4+reg  [m89-verified]
    const int cr = (lane >> 4) * 4, cc = lane & 15;
    #pragma unroll
    for (int mi = 0; mi < 4; mi++) {
        #pragma unroll
        for (int r = 0; r < 4; r++) {
            int row = m0 + wm + mi * 16 + cr + r;
            if (row >= M) continue;
            #pragma unroll
            for (int ni = 0; ni < 4; ni++) {
                int col = n0 + wn + ni * 16 + cc;
                if (col < N) {
                    float v = acc[mi][ni][r];
                    if (bias1) v += bias1[col];
                    if (bias2) v += bias2[col];
                    C[(long)row * ldc + col] = v;
                }
            }
        }
    }
}

// ---------------------------------------------------------------------------
// Layer-0 LSTM step
// ---------------------------------------------------------------------------
__global__ __launch_bounds__(256) void lstm0_kernel(
    const float* __restrict__ GX, const float* __restrict__ hprev,
    float* __restrict__ c_io, const float* __restrict__ Wh,
    float* __restrict__ h_out)
{
    __shared__ float h_s[200 * 33];
    const int k = blockIdx.y, jt = blockIdx.x, tid = threadIdx.x;
    for (int idx = tid; idx < 32 * 200; idx += 256) {
        int b = idx / 200, m = idx % 200;
        h_s[m * 33 + b] = hprev[b * NHID + k * BS + m];
    }
    __syncthreads();
    const int b = tid & 31, jj = tid >> 5;
    const int j = jt * 8 + jj;
    const float* w0 = Wh + (long)(k * 800 + j) * 200;
    const float* w1 = w0 + 200 * 200;
    const float* w2 = w0 + 400 * 200;
    const float* w3 = w0 + 600 * 200;
    float a0 = 0, a1 = 0, a2 = 0, a3 = 0;
    for (int m = 0; m < 200; m++) {
        float hv = h_s[m * 33 + b];
        a0 += hv * w0[m]; a1 += hv * w1[m]; a2 += hv * w2[m]; a3 += hv * w3[m];
    }
    const float* gx = GX + b * NG + k * 800;
    float gi = a0 + gx[j];
    float gf = a1 + gx[200 + j];
    float gg = a2 + gx[400 + j];
    float go = a3 + gx[600 + j];
    int o = b * NHID + k * BS + j;
    float cold = c_io[o];
    float cn = sigmoidf_(gf) * cold + sigmoidf_(gi) * tanhf(gg);
    float hn = sigmoidf_(go) * tanhf(cn);
    c_io[o] = cn;
    h_out[o] = hn;
}

// ---------------------------------------------------------------------------
// Layer-1 LSTM step
// ---------------------------------------------------------------------------
__global__ __launch_bounds__(256) void lstm1_kernel(
    const float* __restrict__ inp, const float* __restrict__ hprev,
    float* __restrict__ c_io, const float* __restrict__ Wi,
    const float* __restrict__ Wh, const float* __restrict__ bih,
    const float* __restrict__ bhh, float* __restrict__ h_out)
{
    __shared__ float h_s[200 * 33];
    __shared__ float x_s[96 * 33];
    const int k = blockIdx.y, jt = blockIdx.x, tid = threadIdx.x;
    for (int idx = tid; idx < 32 * 200; idx += 256) {
        int b = idx / 200, m = idx % 200;
        h_s[m * 33 + b] = hprev[b * NHID + k * BS + m];
    }
    const int b = tid & 31, jj = tid >> 5;
    const int j = jt * 8 + jj;
    const float* wi0 = Wi + (long)(k * 800 + j) * NINP;
    const float* wi1 = wi0 + (long)200 * NINP;
    const float* wi2 = wi0 + (long)400 * NINP;
    const float* wi3 = wi0 + (long)600 * NINP;
    float a0 = 0, a1 = 0, a2 = 0, a3 = 0;
    for (int kt = 0; kt < NINP; kt += 96) {
        __syncthreads();
        for (int idx = tid; idx < 96 * 32; idx += 256) {
            int bb = idx / 96, m = idx % 96;
            x_s[m * 33 + bb] = inp[(long)(bb * 6 + k) * NINP + kt + m];
        }
        __syncthreads();
        for (int m = 0; m < 96; m++) {
            float xv = x_s[m * 33 + b];
            a0 += xv * wi0[kt + m]; a1 += xv * wi1[kt + m];
            a2 += xv * wi2[kt + m]; a3 += xv * wi3[kt + m];
        }
    }
    const float* w0 = Wh + (long)(k * 800 + j) * 200;
    const float* w1 = w0 + 200 * 200;
    const float* w2 = w0 + 400 * 200;
    const float* w3 = w0 + 600 * 200;
    for (int m = 0; m < 200; m++) {
        float hv = h_s[m * 33 + b];
        a0 += hv * w0[m]; a1 += hv * w1[m]; a2 += hv * w2[m]; a3 += hv * w3[m];
    }
    int nb = k * 800;
    float gi = a0 + bih[nb + j] + bhh[nb + j];
    float gf = a1 + bih[nb + 200 + j] + bhh[nb + 200 + j];
    float gg = a2 + bih[nb + 400 + j] + bhh[nb + 400 + j];
    float go = a3 + bih[nb + 600 + j] + bhh[nb + 600 + j];
    int o = b * NHID + k * BS + j;
    float cold = c_io[o];
    float cn = sigmoidf_(gf) * cold + sigmoidf_(gi) * tanhf(gg);
    float hn = sigmoidf_(go) * tanhf(cn);
    c_io[o] = cn;
    h_out[o] = hn;
}

// ---------------------------------------------------------------------------
// Small self-attention + residual + LN. grid=32 (b)
// ---------------------------------------------------------------------------
__global__ __launch_bounds__(256) void att_small_kernel(
    const float* __restrict__ h_in, float* __restrict__ h_out,
    const float* __restrict__ mq, const float* __restrict__ mk,
    const float* __restrict__ mv, const float* __restrict__ mfc,
    const float* __restrict__ mg, const float* __restrict__ mb)
{
    __shared__ float hb[1200];
    __shared__ float qh[384], kh[384], vh[384];
    __shared__ float att[144];
    __shared__ float outp[384];
    __shared__ float o2[1200];
    __shared__ float mu_s[6], rs_s[6];
    const int b = blockIdx.x, tid = threadIdx.x;
    for (int i = tid; i < 1200; i += 256) hb[i] = h_in[b * NHID + i];
    __syncthreads();
    for (int id = tid; id < 1152; id += 256) {
        int which = id / 384, r = id % 384;
        int l = r >> 6, hd = r & 63;
        const float* Mw = which == 0 ? mq : (which == 1 ? mk : mv);
        const float* hr = &hb[l * 200];
        float s = 0;
        for (int jx = 0; jx < 200; jx++) s += hr[jx] * Mw[jx * 64 + hd];
        float* dst = which == 0 ? qh : (which == 1 ? kh : vh);
        dst[r] = s;
    }
    __syncthreads();
    for (int id = tid; id < 144; id += 256) {
        int h = id / 36, r = id % 36, q = r / 6, kk = r % 6;
        float s = 0;
        for (int d = 0; d < 16; d++) s += qh[q * 64 + h * 16 + d] * kh[kk * 64 + h * 16 + d];
        att[(h * 6 + q) * 6 + kk] = s * 0.25f;
    }
    __syncthreads();
    if (tid < 24) {
        float* a = &att[tid * 6];
        float mx = a[0];
        for (int i = 1; i < 6; i++) mx = fmaxf(mx, a[i]);
        float sm = 0;
        for (int i = 0; i < 6; i++) { a[i] = expf(a[i] - mx); sm += a[i]; }
        float inv = 1.f / sm;
        for (int i = 0; i < 6; i++) a[i] *= inv;
    }
    __syncthreads();
    for (int id = tid; id < 384; id += 256) {
        int q = id >> 6, hd = id & 63, h = hd >> 4;
        float s = 0;
        for (int kk = 0; kk < 6; kk++) s += att[(h * 6 + q) * 6 + kk] * vh[kk * 64 + hd];
        outp[id] = s;
    }
    __syncthreads();
    for (int id = tid; id < 1200; id += 256) {
        int q = id / 200, jx = id % 200;
        float s = 0;
        for (int d = 0; d < 64; d++) s += outp[q * 64 + d] * mfc[d * 200 + jx];
        o2[id] = s + hb[id];
    }
    __syncthreads();
    if (tid < 6) {
        float s = 0, s2 = 0;
        for (int jx = 0; jx < 200; jx++) { float v = o2[tid * 200 + jx]; s += v; s2 += v * v; }
        float mu = s / 200.f;
        float var = s2 / 200.f - mu * mu;
        mu_s[tid] = mu;
        rs_s[tid] = 1.0f / sqrtf(var + 1e-5f);
    }
    __syncthreads();
    for (int id = tid; id < 1200; id += 256) {
        int q = id / 200, jx = id % 200;
        h_out[b * NHID + id] = (o2[id] - mu_s[q]) * rs_s[q] * mg[jx] + mb[jx];
    }
}

// ---------------------------------------------------------------------------
// Layer-1 attention (8 heads, dk=200), all fp32. grid=32 (b)
// ---------------------------------------------------------------------------
__global__ __launch_bounds__(256) void att1_kernel(
    const float* __restrict__ QH, const float* __restrict__ KH,
    const float* __restrict__ VH, float* __restrict__ attV)
{
    __shared__ float att[288];
    const int b = blockIdx.x, tid = threadIdx.x;
    const float* qb = QH + b * 9600;
    const float* kb = KH + b * 9600;
    const float* vb = VH + b * 9600;
    for (int id = tid; id < 288; id += 256) {
        int h = id / 36, r = id % 36, q = r / 6, kk = r % 6;
        const float* qr = qb + q * L1D + h * 200;
        const float* kr = kb + kk * L1D + h * 200;
        float s = 0;
        for (int d = 0; d < 200; d++) s += qr[d] * kr[d];
        att[(h * 6 + q) * 6 + kk] = s * 0.07071067811865475f;
    }
    __syncthreads();
    if (tid < 48) {
        float* a = &att[tid * 6];
        float mx = a[0];
        for (int i = 1; i < 6; i++) mx = fmaxf(mx, a[i]);
        float sm = 0;
        for (int i = 0; i < 6; i++) { a[i] = expf(a[i] - mx); sm += a[i]; }
        float inv = 1.f / sm;
        for (int i = 0; i < 6; i++) a[i] *= inv;
    }
    __syncthreads();
    for (int id = tid; id < 9600; id += 256) {
        int q = id / L1D, hd = id % L1D, h = hd / 200;
        float s = 0;
        for (int kk = 0; kk < 6; kk++) s += att[(h * 6 + q) * 6 + kk] * vb[kk * L1D + hd];
        attV[b * 9600 + id] = s;
    }
}

// ---------------------------------------------------------------------------
// LayerNorm over n columns. grid = rows
// ---------------------------------------------------------------------------
__global__ __launch_bounds__(256) void ln_kernel(
    const float* __restrict__ X, float* __restrict__ Y,
    const float* __restrict__ g, const float* __restrict__ bta, int n)
{
    const int row = blockIdx.x, tid = threadIdx.x;
    const float* xr = X + (long)row * n;
    float s = 0, s2 = 0;
    for (int i = tid; i < n; i += 256) { float v = xr[i]; s += v; s2 += v * v; }
    for (int off = 32; off; off >>= 1) { s += __shfl_down(s, off); s2 += __shfl_down(s2, off); }
    __shared__ float rs[8], rq[8];
    int wid = tid >> 6, lane = tid & 63;
    if (lane == 0) { rs[wid] = s; rq[wid] = s2; }
    __syncthreads();
    if (tid == 0) {
        float a = 0, a2 = 0;
        for (int w = 0; w < 4; w++) { a += rs[w]; a2 += rq[w]; }
        float mu = a / n;
        float var = a2 / n - mu * mu;
        rs[0] = mu;
        rq[0] = 1.0f / sqrtf(var + 1e-5f);
    }
    __syncthreads();
    float mu = rs[0], rstd = rq[0];
    for (int i = tid; i < n; i += 256) Y[(long)row * n + i] = (xr[i] - mu) * rstd * g[i] + bta[i];
}

// ---------------------------------------------------------------------------
extern "C" void kernel_launch(void* const* d_in, const int* in_sizes, int n_in,
                              void* d_out, int out_size, void* d_ws, size_t ws_size,
                              hipStream_t stream)
{
    const int*   tokens = (const int*)  d_in[0];
    const float* h0     = (const float*)d_in[1];
    const float* c0     = (const float*)d_in[2];
    const float* emb    = (const float*)d_in[3];
    const float* Wi     = (const float*)d_in[4];
    const float* Wh     = (const float*)d_in[5];
    const float* bih    = (const float*)d_in[6];
    const float* bhh    = (const float*)d_in[7];
    const float* mq     = (const float*)d_in[8];
    const float* mk     = (const float*)d_in[9];
    const float* mv     = (const float*)d_in[10];
    const float* mfc    = (const float*)d_in[11];
    const float* mg     = (const float*)d_in[12];
    const float* mb     = (const float*)d_in[13];
    const float* lq     = (const float*)d_in[14];
    const float* lk     = (const float*)d_in[15];
    const float* lv     = (const float*)d_in[16];
    const float* lfc    = (const float*)d_in[17];
    const float* lg     = (const float*)d_in[18];
    const float* lb     = (const float*)d_in[19];
    const float* dec_w  = (const float*)d_in[20];
    const float* dec_b  = (const float*)d_in[21];
    float* out = (float*)d_out;

    // workspace carve-up (floats) — round-1-proven ~114.7 MB footprint
    float* p = (float*)d_ws;
    float* GX0  = p; p += (long)ROWS * NG;        // 1024*4800
    float* out0 = p; p += (long)ROWS * NHID;      // 1024*1200
    float* out1 = p; p += (long)ROWS * NHID;
    float* KH1  = p; p += (long)ROWS * 6 * L1D;   // 6144*1600 fp32
    float* VH1  = p; p += (long)ROWS * 6 * L1D;
    float* QH   = p; p += 192 * L1D;
    float* attV = p; p += 192 * L1D;
    float* FCb  = p; p += 192 * NINP;
    float* inp  = p; p += 192 * NINP;
    float* htmp = p; p += BZ * NHID;
    float* cb0  = p; p += BZ * NHID;
    float* cb1  = p; p += BZ * NHID;

    const int ST = BZ * NHID;

    hipMemcpyAsync(cb0, c0,      ST * sizeof(float), hipMemcpyDeviceToDevice, stream);
    hipMemcpyAsync(cb1, c0 + ST, ST * sizeof(float), hipMemcpyDeviceToDevice, stream);

    // GX0 = emb[tokens] @ Wi^T + bih + bhh   (bf16x3, gather fused)
    gemm_mfma_kernel<3, false><<<dim3(38, 8), 256, 0, stream>>>(
        emb, Wi, bih, bhh, GX0, ROWS, NG, NINP, NG, tokens);

    // ---- Phase A: layer-0 scan ----
    for (int t = 0; t < TT; t++) {
        const float* hp = (t == 0) ? h0 : out0 + (t - 1) * ST;
        lstm0_kernel<<<dim3(25, 6), 256, 0, stream>>>(
            GX0 + (long)t * BZ * NG, hp, cb0, Wh, htmp);
        att_small_kernel<<<BZ, 256, 0, stream>>>(htmp, out0 + t * ST, mq, mk, mv, mfc, mg, mb);
    }

    // KH1/VH1 = out0 (6144,200) @ lk / lv   (bf16x3, B transposed-source)
    gemm_mfma_kernel<3, true><<<dim3(13, 48), 256, 0, stream>>>(
        out0, lk, nullptr, nullptr, KH1, ROWS * 6, L1D, BS, L1D, nullptr);
    gemm_mfma_kernel<3, true><<<dim3(13, 48), 256, 0, stream>>>(
        out0, lv, nullptr, nullptr, VH1, ROWS * 6, L1D, BS, L1D, nullptr);

    // ---- Phase B: layer-1 scan ----
    for (int t = 0; t < TT; t++) {
        const float* hp = (t == 0) ? h0 + ST : out1 + (t - 1) * ST;
        // QH = h (192,200) @ lq (200,1600)   (bf16x3)
        gemm_mfma_kernel<3, true><<<dim3(13, 2), 256, 0, stream>>>(
            hp, lq, nullptr, nullptr, QH, 192, L1D, BS, L1D, nullptr);
        att1_kernel<<<BZ, 256, 0, stream>>>(
            QH, KH1 + (long)t * BZ * 6 * L1D, VH1 + (long)t * BZ * 6 * L1D, attV);
        // FC = attV (192,1600) @ lfc (1600,2400)   (bf16x3)
        gemm_mfma_kernel<3, true><<<dim3(19, 2), 256, 0, stream>>>(
            attV, lfc, nullptr, nullptr, FCb, 192, NINP, L1D, NINP, nullptr);
        ln_kernel<<<192, 256, 0, stream>>>(FCb, inp, lg, lb, NINP);
        lstm1_kernel<<<dim3(25, 6), 256, 0, stream>>>(inp, hp, cb1, Wi, Wh, bih, bhh, htmp);
        att_small_kernel<<<BZ, 256, 0, stream>>>(htmp, out1 + t * ST, mq, mk, mv, mfc, mg, mb);
    }

    // decode: out1 (1024,1200) @ dec_w^T (16000,1200) + dec_b  (plain bf16,
    // outside the recurrence — error not amplified)
    gemm_mfma_kernel<1, false><<<dim3(125, 8), 256, 0, stream>>>(
        out1, dec_w, dec_b, nullptr, out, ROWS, NTOK, NHID, NTOK, nullptr);

    // final states
    long off = (long)ROWS * NTOK;
    hipMemcpyAsync(out + off,          out0 + 31 * ST, ST * sizeof(float), hipMemcpyDeviceToDevice, stream);
    hipMemcpyAsync(out + off + ST,     out1 + 31 * ST, ST * sizeof(float), hipMemcpyDeviceToDevice, stream);
    hipMemcpyAsync(out + off + 2 * ST, cb0,            ST * sizeof(float), hipMemcpyDeviceToDevice, stream);
    hipMemcpyAsync(out + off + 3 * ST, cb1,            ST * sizeof(float), hipMemcpyDeviceToDevice, stream);
}